// Round 7
// baseline (216.448 us; speedup 1.0000x reference)
//
#include <hip/hip_runtime.h>
#include <math.h>

#define NNODES 16384
#define NV 16385
#define NEDGE 131072
#define NEG -1e30f
#define SCALE 2.8853900817779268f  // 2*log2(e): tanh(x) = 1 - 2/(exp2(SCALE*x)+1)

typedef __attribute__((ext_vector_type(8))) short short8;
typedef __attribute__((ext_vector_type(8))) unsigned short ushort8;
typedef __attribute__((ext_vector_type(4))) float f32x4;

// Scratch as static device globals. Counters are reset to 0 by the final block
// each launch (and .bss-zero on first launch), so every graph replay is identical.
__device__ float g_part[4 * NEDGE];  // per-h-tile partial edge sums
__device__ float g_mats[32 * 64];    // 32 segment matrices (8x8, row-major)
__device__ float g_gold;             // gold-path sum
__device__ int g_scnt[32];           // per-segment arrival counters
__device__ int g_done;               // segment-done counter

__device__ __forceinline__ unsigned short f2bf(float x) {
  union { float f; unsigned int u; } c; c.f = x;
  unsigned int u = c.u;
  unsigned int r = (u + 0x7fffu + ((u >> 16) & 1u)) >> 16;  // RNE
  return (unsigned short)r;
}
__device__ __forceinline__ float bf2f(unsigned short u) {
  union { unsigned int u; float f; } c; c.u = ((unsigned int)u) << 16;
  return c.f;
}

__device__ __forceinline__ float lse8(float x0, float x1, float x2, float x3,
                                      float x4, float x5, float x6, float x7) {
  float m = fmaxf(fmaxf(fmaxf(x0, x1), fmaxf(x2, x3)),
                  fmaxf(fmaxf(x4, x5), fmaxf(x6, x7)));
  float s = __expf(x0 - m) + __expf(x1 - m) + __expf(x2 - m) + __expf(x3 - m) +
            __expf(x4 - m) + __expf(x5 - m) + __expf(x6 - m) + __expf(x7 - m);
  return m + __logf(s);
}

// Full-wave 8x8 log-semiring matmul: lane l=(i*8+j) holds A[i][j], B[i][j];
// returns (A (X) B)[i][j] = lse_k(A[i][k] + B[k][j]).  i8 = (l>>3)<<3, j = l&7.
__device__ __forceinline__ float comb8(float A, float B, int i8, int j) {
  float x0 = __shfl(A, i8 + 0) + __shfl(B, 0 + j);
  float x1 = __shfl(A, i8 + 1) + __shfl(B, 8 + j);
  float x2 = __shfl(A, i8 + 2) + __shfl(B, 16 + j);
  float x3 = __shfl(A, i8 + 3) + __shfl(B, 24 + j);
  float x4 = __shfl(A, i8 + 4) + __shfl(B, 32 + j);
  float x5 = __shfl(A, i8 + 5) + __shfl(B, 40 + j);
  float x6 = __shfl(A, i8 + 6) + __shfl(B, 48 + j);
  float x7 = __shfl(A, i8 + 7) + __shfl(B, 56 + j);
  return lse8(x0, x1, x2, x3, x4, x5, x6, x7);
}

// Single mega-kernel. Grid (4 h-tiles, 256 node-tiles of 64), 256 threads.
// Phase 1 (MFMA): A[p][h]=emb[p]@W1_top, B[i][h]=emb[i]@W1_bot -> LDS (bf16, pre-scaled).
// Phase 2: per-edge partial sums -> g_part.
// Phase 3 (last block of each 32-block segment): softplus+gold+chunk recurrence,
//          8 chunk mats -> 1 segment mat (shfl log-matmul) -> g_mats.
// Phase 4 (last segment): combine 32 segment mats, write out, reset counters.
__global__ __launch_bounds__(256, 5) void k_mega(const float* __restrict__ emb,
                                                 const float* __restrict__ W1,
                                                 const float* __restrict__ b1,
                                                 const float* __restrict__ W2,
                                                 const float* __restrict__ b2,
                                                 float* __restrict__ out) {
  __shared__ __align__(16) unsigned short lds[15072];  // 29.4 KB
  unsigned short* Es  = lds;                   // [80][72] emb tile (pitch 72)
  unsigned short* WtA = lds + 5760;            // [64][72]
  unsigned short* WtB = lds + 10368;           // [64][72]
  unsigned short* CA  = lds;                   // [80][72]  (aliases Es, phase 2)
  unsigned short* CB  = lds + 5760;            // [64][72]  (aliases WtA)
  unsigned short* W2s = lds + 14976;           // [64]  bf16(-2*W2)
  float* Wsum = (float*)(lds + 15040);         // [8]   per-granule sum of W2
  // Consumer-phase aliases (used after a barrier once CA/CB are dead):
  float* wf  = (float*)lds;                    // [64][64] chunk-step values
  float* red = (float*)(lds + 8192);           // [256] gold reduction
  float* m8  = (float*)(lds + 8704);           // [8][64] chunk matrices
  float* l2m = (float*)(lds + 9728);           // [4][64] wave partial products
  __shared__ int s_tick;

  const int t = threadIdx.x;
  const int h0 = blockIdx.x << 6;
  const int i0 = blockIdx.y << 6;
  const int seg = blockIdx.y >> 3;   // 32 blocks (4 hx x 8 vy) per segment
  const int wv = t >> 6, lane = t & 63;
  const int l15 = lane & 15, quad = lane >> 4;

  // W2 prep (region disjoint from staging; visible after first barrier).
  if (t < 64) W2s[t] = f2bf(-2.f * W2[h0 + t]);
  if (t < 8) {
    float s = 0.f;
#pragma unroll
    for (int jj = 0; jj < 8; ++jj) s += W2[h0 + (t << 3) + jj];
    Wsum[t] = s;
  }

  f32x4 accA[5], accB[4];
#pragma unroll
  for (int m = 0; m < 5; ++m) accA[m] = (f32x4){0.f, 0.f, 0.f, 0.f};
#pragma unroll
  for (int m = 0; m < 4; ++m) accB[m] = (f32x4){0.f, 0.f, 0.f, 0.f};

  for (int hk = 0; hk < 2; ++hk) {  // K=128 in two 64-halves
    if (hk) __syncthreads();
    // Stage emb rows [i0-7, i0+73) x 64 k -> bf16. 80 rows x 16 float4.
#pragma unroll
    for (int it = 0; it < 5; ++it) {
      int idx = t + (it << 8);
      int row = idx >> 4;
      int k4 = (idx & 15) << 2;
      int v = i0 - 7 + row;
      float4 g = make_float4(0.f, 0.f, 0.f, 0.f);
      if (v >= 0 && v < NV) g = *(const float4*)&emb[v * 128 + (hk << 6) + k4];
      uint2 pk;
      pk.x = f2bf(g.x) | ((unsigned int)f2bf(g.y) << 16);
      pk.y = f2bf(g.z) | ((unsigned int)f2bf(g.w) << 16);
      *(uint2*)&Es[row * 72 + k4] = pk;
    }
    // Stage weight tiles transposed: Wt[n][k] = W1[.][h0+n].
    {
      const int n = t & 63;
      const int kg = (t >> 6) << 4;
#pragma unroll
      for (int kk = 0; kk < 16; kk += 2) {
        int k = (hk << 6) + kg + kk;
        float a0 = W1[k * 256 + h0 + n];
        float a1 = W1[(k + 1) * 256 + h0 + n];
        *(unsigned int*)&WtA[n * 72 + kg + kk] = f2bf(a0) | ((unsigned int)f2bf(a1) << 16);
        float c0 = W1[(128 + k) * 256 + h0 + n];
        float c1 = W1[(128 + k + 1) * 256 + h0 + n];
        *(unsigned int*)&WtB[n * 72 + kg + kk] = f2bf(c0) | ((unsigned int)f2bf(c1) << 16);
      }
    }
    __syncthreads();
    const int kq = quad << 3;
#pragma unroll
    for (int kc = 0; kc < 2; ++kc) {
      const int kb = (kc << 5) + kq;
      short8 fA = *(const short8*)&WtA[((wv << 4) + l15) * 72 + kb];
      short8 fB = *(const short8*)&WtB[((wv << 4) + l15) * 72 + kb];
#pragma unroll
      for (int mf = 0; mf < 5; ++mf) {
        short8 a = *(const short8*)&Es[((mf << 4) + l15) * 72 + kb];
        accA[mf] = __builtin_amdgcn_mfma_f32_16x16x32_bf16(a, fA, accA[mf], 0, 0, 0);
      }
#pragma unroll
      for (int mf = 0; mf < 4; ++mf) {
        short8 a = *(const short8*)&Es[(8 + (mf << 4) + l15) * 72 + kb];
        accB[mf] = __builtin_amdgcn_mfma_f32_16x16x32_bf16(a, fB, accB[mf], 0, 0, 0);
      }
    }
  }
  __syncthreads();
  // Store C tiles (bf16, pre-scaled). C/D frag: row = quad*4+reg, col = lane&15.
  const int hcol = (wv << 4) + l15;
  const float b1s = b1[h0 + hcol];
#pragma unroll
  for (int mf = 0; mf < 5; ++mf) {
    int rb = (mf << 4) + (quad << 2);
#pragma unroll
    for (int rr = 0; rr < 4; ++rr)
      CA[(rb + rr) * 72 + hcol] = f2bf((accA[mf][rr] + b1s) * SCALE);
  }
#pragma unroll
  for (int mf = 0; mf < 4; ++mf) {
    int rb = (mf << 4) + (quad << 2);
#pragma unroll
    for (int rr = 0; rr < 4; ++rr)
      CB[(rb + rr) * 72 + hcol] = f2bf(accB[mf][rr] * SCALE);
  }
  __syncthreads();
  // Edge phase: thread t -> k = t&7, qb = t>>3; edges q = qb, qb+32.
  const int k = t & 7;
  const int qb = t >> 3;
  float part[2] = {0.f, 0.f};
#pragma unroll
  for (int g = 0; g < 8; ++g) {
    const int s = (g + (k << 1)) & 7;  // granule rotation: conflict-uniform banks
    ushort8 wv8 = *(const ushort8*)&W2s[s << 3];
    float m2w[8];
#pragma unroll
    for (int jj = 0; jj < 8; ++jj) m2w[jj] = bf2f(wv8[jj]);
    const float ws = Wsum[s];
#pragma unroll
    for (int j = 0; j < 2; ++j) {
      const int q = qb + (j << 5);
      ushort8 a8 = *(const ushort8*)&CA[(7 + q - k) * 72 + (s << 3)];
      ushort8 b8 = *(const ushort8*)&CB[q * 72 + (s << 3)];
      float p = part[j];
#pragma unroll
      for (int jj = 0; jj < 8; ++jj) {
        float x = bf2f(a8[jj]) + bf2f(b8[jj]);
        float e = __builtin_amdgcn_exp2f(x);
        float r = __builtin_amdgcn_rcpf(e + 1.f);
        p = fmaf(r, m2w[jj], p);
      }
      part[j] = p + ws;
    }
  }
  const int ebase = blockIdx.x * NEDGE + (blockIdx.y << 9) + t;
  g_part[ebase] = part[0];
  g_part[ebase + 256] = part[1];

  // ---- Segment ticket: 32nd arriver of this segment becomes its consumer.
  __threadfence();
  __syncthreads();
  if (t == 0) s_tick = atomicAdd(&g_scnt[seg], 1);
  __syncthreads();
  if (s_tick != 31) return;
  __threadfence();  // acquire: all 32 producers' g_part stores visible

  // ---- Phase 3: consumer for segment `seg` = edges [seg*4096, seg*4096+4096).
  const int b = seg;
  const float b2v = b2[0];
  float gold = 0.f;
#pragma unroll
  for (int it = 0; it < 4; ++it) {
    const int e4 = t + (it << 8);
    const int gidx = (b << 10) + e4;
    float4 s0 = *(const float4*)&g_part[gidx << 2];
    float4 s1 = *(const float4*)&g_part[NEDGE + (gidx << 2)];
    float4 s2 = *(const float4*)&g_part[2 * NEDGE + (gidx << 2)];
    float4 s3 = *(const float4*)&g_part[3 * NEDGE + (gidx << 2)];
    float d0 = s0.x + s1.x + s2.x + s3.x + b2v;
    float d1 = s0.y + s1.y + s2.y + s3.y + b2v;
    float d2 = s0.z + s1.z + s2.z + s3.z + b2v;
    float d3 = s0.w + s1.w + s2.w + s3.w + b2v;
    d0 = fmaxf(d0, 0.f) + log1pf(__expf(-fabsf(d0)));
    d1 = fmaxf(d1, 0.f) + log1pf(__expf(-fabsf(d1)));
    d2 = fmaxf(d2, 0.f) + log1pf(__expf(-fabsf(d2)));
    d3 = fmaxf(d3, 0.f) + log1pf(__expf(-fabsf(d3)));
    const int q = e4 << 2;
    const int cl = q >> 9, r = q & 511;
    const int s = r >> 3, kk = r & 7;
    *(float4*)&wf[s * 64 + (cl << 3) + kk] = make_float4(d0, d1, d2, d3);
    if ((t & 1) == 0) gold += d0;  // k==0 edges (gold path)
  }
  red[t] = gold;
  __syncthreads();
  if (b == 0 && t == 0) {
    // node i = s+1 has valid preds kk <= s only: poison invalid d with +1e30
    for (int s = 0; s < 7; ++s)
      for (int kk = s + 1; kk < 8; ++kk) wf[s * 64 + kk] = 1e30f;
  }
  for (int o = 128; o > 0; o >>= 1) {
    __syncthreads();
    if (t < o) red[t] += red[t + o];
  }
  __syncthreads();
  if (t == 0) atomicAdd(&g_gold, red[0]);
  if (t < 64) {  // wave 0: 8 chunk recurrences (8 lanes each)
    const int g = t >> 3, j = t & 7;
    float P[8];
#pragma unroll
    for (int kk = 0; kk < 8; ++kk) P[kk] = (kk == j) ? 0.f : NEG;
    for (int s = 0; s < 64; ++s) {
      const float* wp = &wf[s * 64 + (g << 3)];
      float4 wa = *(const float4*)wp;
      float4 wb = *(const float4*)(wp + 4);
      float nv = lse8(P[0] - wa.x, P[1] - wa.y, P[2] - wa.z, P[3] - wa.w,
                      P[4] - wb.x, P[5] - wb.y, P[6] - wb.z, P[7] - wb.w);
#pragma unroll
      for (int kk = 7; kk > 0; --kk) P[kk] = P[kk - 1];
      P[0] = nv;
    }
    // Store chunk mats row-major: m8[g][k*8+j] = T[k][j].
#pragma unroll
    for (int kk = 0; kk < 8; ++kk) m8[(g << 6) + (kk << 3) + j] = P[kk];
    // Combine 8 chunk mats -> segment mat (same wave; DS ops are in-order).
    const int i8 = (t >> 3) << 3;
    float R = m8[t];  // chunk 0, lane t = [i][j]
#pragma unroll
    for (int g2 = 1; g2 < 8; ++g2) R = comb8(m8[(g2 << 6) + t], R, i8, j);
    g_mats[(b << 6) + t] = R;
  }
  __threadfence();
  __syncthreads();
  if (t == 0) s_tick = atomicAdd(&g_done, 1);
  __syncthreads();
  if (s_tick != 31) return;
  __threadfence();  // acquire: all 32 segment mats visible

  // ---- Phase 4: final combine of 32 segment matrices. Wave w: segs 8w..8w+7.
  {
    const int l = t & 63, w = t >> 6;
    const int i8 = (l >> 3) << 3, j = l & 7;
    float G = g_mats[((w << 3) << 6) + l];
#pragma unroll
    for (int s2 = 1; s2 < 8; ++s2)
      G = comb8(g_mats[(((w << 3) + s2) << 6) + l], G, i8, j);
    l2m[(w << 6) + l] = G;
    __syncthreads();
    if (t < 64) {
      float G2 = l2m[t];
#pragma unroll
      for (int w2 = 1; w2 < 4; ++w2) G2 = comb8(l2m[(w2 << 6) + t], G2, i8, j);
      if (t == 0) {
        float gv = atomicAdd(&g_gold, 0.f);  // atomic read
        out[0] = gv + G2;                    // gold + (prod)[0][0]
        g_gold = 0.f;
        g_done = 0;
      }
    }
    if (t < 32) g_scnt[t] = 0;  // reset for next launch / graph replay
  }
}

extern "C" void kernel_launch(void* const* d_in, const int* in_sizes, int n_in,
                              void* d_out, int out_size, void* d_ws, size_t ws_size,
                              hipStream_t stream) {
  const float* emb = (const float*)d_in[0];
  const float* W1 = (const float*)d_in[1];
  const float* b1 = (const float*)d_in[2];
  const float* W2 = (const float*)d_in[3];
  const float* b2 = (const float*)d_in[4];
  float* out = (float*)d_out;
  hipLaunchKernelGGL(k_mega, dim3(4, 256), dim3(256), 0, stream,
                     emb, W1, b1, W2, b2, out);
}

// Round 8
// 117.679 us; speedup vs baseline: 1.8393x; 1.8393x over previous
//
#include <hip/hip_runtime.h>
#include <math.h>

#define NNODES 16384
#define NV 16385
#define NEDGE 131072
#define NEG -1e30f
#define SCALE 2.8853900817779268f  // 2*log2(e): tanh(x) = 1 - 2/(exp2(SCALE*x)+1)

typedef __attribute__((ext_vector_type(8))) short short8;
typedef __attribute__((ext_vector_type(8))) unsigned short ushort8;
typedef __attribute__((ext_vector_type(4))) float f32x4;

// Scratch as static device globals. g_gold/g_done are reset by the final tail
// block each launch (.bss-zero on first launch) -> graph replays are identical.
__device__ float g_part[4 * NEDGE];  // per-h-tile partial edge sums
__device__ float g_mats[32 * 64];    // 32 segment matrices (8x8, row-major)
__device__ float g_gold;             // gold-path sum
__device__ int g_done;               // segment-done counter

__device__ __forceinline__ unsigned short f2bf(float x) {
  union { float f; unsigned int u; } c; c.f = x;
  unsigned int u = c.u;
  unsigned int r = (u + 0x7fffu + ((u >> 16) & 1u)) >> 16;  // RNE
  return (unsigned short)r;
}
__device__ __forceinline__ float bf2f(unsigned short u) {
  union { unsigned int u; float f; } c; c.u = ((unsigned int)u) << 16;
  return c.f;
}

__device__ __forceinline__ float lse8(float x0, float x1, float x2, float x3,
                                      float x4, float x5, float x6, float x7) {
  float m = fmaxf(fmaxf(fmaxf(x0, x1), fmaxf(x2, x3)),
                  fmaxf(fmaxf(x4, x5), fmaxf(x6, x7)));
  float s = __expf(x0 - m) + __expf(x1 - m) + __expf(x2 - m) + __expf(x3 - m) +
            __expf(x4 - m) + __expf(x5 - m) + __expf(x6 - m) + __expf(x7 - m);
  return m + __logf(s);
}

// Full-wave 8x8 log-semiring matmul: lane l=(i*8+j) holds A[i][j], B[i][j];
// returns (A (X) B)[i][j] = lse_k(A[i][k] + B[k][j]).  i8 = (l>>3)<<3, j = l&7.
__device__ __forceinline__ float comb8(float A, float B, int i8, int j) {
  float x0 = __shfl(A, i8 + 0) + __shfl(B, 0 + j);
  float x1 = __shfl(A, i8 + 1) + __shfl(B, 8 + j);
  float x2 = __shfl(A, i8 + 2) + __shfl(B, 16 + j);
  float x3 = __shfl(A, i8 + 3) + __shfl(B, 24 + j);
  float x4 = __shfl(A, i8 + 4) + __shfl(B, 32 + j);
  float x5 = __shfl(A, i8 + 5) + __shfl(B, 40 + j);
  float x6 = __shfl(A, i8 + 6) + __shfl(B, 48 + j);
  float x7 = __shfl(A, i8 + 7) + __shfl(B, 56 + j);
  return lse8(x0, x1, x2, x3, x4, x5, x6, x7);
}

// Fused projection + edge kernel (R5-proven). Grid (4 h-tiles, 256 node-tiles), 256 thr.
// No device fences here — plain stores to g_part; kernel boundary publishes them.
__global__ __launch_bounds__(256, 5) void k12_fused(const float* __restrict__ emb,
                                                    const float* __restrict__ W1,
                                                    const float* __restrict__ b1,
                                                    const float* __restrict__ W2) {
  __shared__ __align__(16) unsigned short lds[15072];  // 29.4 KB
  unsigned short* Es  = lds;                   // [80][72] emb tile (pitch 72)
  unsigned short* WtA = lds + 5760;            // [64][72]
  unsigned short* WtB = lds + 10368;           // [64][72]
  unsigned short* CA  = lds;                   // [80][72]  (aliases Es, phase 2)
  unsigned short* CB  = lds + 5760;            // [64][72]  (aliases WtA)
  unsigned short* W2s = lds + 14976;           // [64]  bf16(-2*W2)
  float* Wsum = (float*)(lds + 15040);         // [8]   per-granule sum of W2

  const int t = threadIdx.x;
  const int h0 = blockIdx.x << 6;
  const int i0 = blockIdx.y << 6;
  const int wv = t >> 6, lane = t & 63;
  const int l15 = lane & 15, quad = lane >> 4;

  if (t < 64) W2s[t] = f2bf(-2.f * W2[h0 + t]);
  if (t < 8) {
    float s = 0.f;
#pragma unroll
    for (int jj = 0; jj < 8; ++jj) s += W2[h0 + (t << 3) + jj];
    Wsum[t] = s;
  }

  f32x4 accA[5], accB[4];
#pragma unroll
  for (int m = 0; m < 5; ++m) accA[m] = (f32x4){0.f, 0.f, 0.f, 0.f};
#pragma unroll
  for (int m = 0; m < 4; ++m) accB[m] = (f32x4){0.f, 0.f, 0.f, 0.f};

  for (int hk = 0; hk < 2; ++hk) {  // K=128 in two 64-halves
    if (hk) __syncthreads();
#pragma unroll
    for (int it = 0; it < 5; ++it) {
      int idx = t + (it << 8);
      int row = idx >> 4;
      int k4 = (idx & 15) << 2;
      int v = i0 - 7 + row;
      float4 g = make_float4(0.f, 0.f, 0.f, 0.f);
      if (v >= 0 && v < NV) g = *(const float4*)&emb[v * 128 + (hk << 6) + k4];
      uint2 pk;
      pk.x = f2bf(g.x) | ((unsigned int)f2bf(g.y) << 16);
      pk.y = f2bf(g.z) | ((unsigned int)f2bf(g.w) << 16);
      *(uint2*)&Es[row * 72 + k4] = pk;
    }
    {
      const int n = t & 63;
      const int kg = (t >> 6) << 4;
#pragma unroll
      for (int kk = 0; kk < 16; kk += 2) {
        int k = (hk << 6) + kg + kk;
        float a0 = W1[k * 256 + h0 + n];
        float a1 = W1[(k + 1) * 256 + h0 + n];
        *(unsigned int*)&WtA[n * 72 + kg + kk] = f2bf(a0) | ((unsigned int)f2bf(a1) << 16);
        float c0 = W1[(128 + k) * 256 + h0 + n];
        float c1 = W1[(128 + k + 1) * 256 + h0 + n];
        *(unsigned int*)&WtB[n * 72 + kg + kk] = f2bf(c0) | ((unsigned int)f2bf(c1) << 16);
      }
    }
    __syncthreads();
    const int kq = quad << 3;
#pragma unroll
    for (int kc = 0; kc < 2; ++kc) {
      const int kb = (kc << 5) + kq;
      short8 fA = *(const short8*)&WtA[((wv << 4) + l15) * 72 + kb];
      short8 fB = *(const short8*)&WtB[((wv << 4) + l15) * 72 + kb];
#pragma unroll
      for (int mf = 0; mf < 5; ++mf) {
        short8 a = *(const short8*)&Es[((mf << 4) + l15) * 72 + kb];
        accA[mf] = __builtin_amdgcn_mfma_f32_16x16x32_bf16(a, fA, accA[mf], 0, 0, 0);
      }
#pragma unroll
      for (int mf = 0; mf < 4; ++mf) {
        short8 a = *(const short8*)&Es[(8 + (mf << 4) + l15) * 72 + kb];
        accB[mf] = __builtin_amdgcn_mfma_f32_16x16x32_bf16(a, fB, accB[mf], 0, 0, 0);
      }
    }
  }
  __syncthreads();
  const int hcol = (wv << 4) + l15;
  const float b1s = b1[h0 + hcol];
#pragma unroll
  for (int mf = 0; mf < 5; ++mf) {
    int rb = (mf << 4) + (quad << 2);
#pragma unroll
    for (int rr = 0; rr < 4; ++rr)
      CA[(rb + rr) * 72 + hcol] = f2bf((accA[mf][rr] + b1s) * SCALE);
  }
#pragma unroll
  for (int mf = 0; mf < 4; ++mf) {
    int rb = (mf << 4) + (quad << 2);
#pragma unroll
    for (int rr = 0; rr < 4; ++rr)
      CB[(rb + rr) * 72 + hcol] = f2bf(accB[mf][rr] * SCALE);
  }
  __syncthreads();
  const int k = t & 7;
  const int qb = t >> 3;
  float part[2] = {0.f, 0.f};
#pragma unroll
  for (int g = 0; g < 8; ++g) {
    const int s = (g + (k << 1)) & 7;  // granule rotation: conflict-uniform banks
    ushort8 wv8 = *(const ushort8*)&W2s[s << 3];
    float m2w[8];
#pragma unroll
    for (int jj = 0; jj < 8; ++jj) m2w[jj] = bf2f(wv8[jj]);
    const float ws = Wsum[s];
#pragma unroll
    for (int j = 0; j < 2; ++j) {
      const int q = qb + (j << 5);
      ushort8 a8 = *(const ushort8*)&CA[(7 + q - k) * 72 + (s << 3)];
      ushort8 b8 = *(const ushort8*)&CB[q * 72 + (s << 3)];
      float p = part[j];
#pragma unroll
      for (int jj = 0; jj < 8; ++jj) {
        float x = bf2f(a8[jj]) + bf2f(b8[jj]);
        float e = __builtin_amdgcn_exp2f(x);
        float r = __builtin_amdgcn_rcpf(e + 1.f);
        p = fmaf(r, m2w[jj], p);
      }
      part[j] = p + ws;
    }
  }
  const int ebase = blockIdx.x * NEDGE + (blockIdx.y << 9) + t;
  g_part[ebase] = part[0];
  g_part[ebase + 256] = part[1];
}

// K_tail: 32 blocks x 256. Block b: edges [b*4096,(b+1)*4096) -> softplus + gold
// + 8 chunk recurrences -> 1 segment matrix (in-wave comb8). Last block (ticket)
// combines 32 segment matrices and writes out. Only 33 device fences total.
__global__ __launch_bounds__(256) void k_tail(const float* __restrict__ b2,
                                              float* __restrict__ out) {
  __shared__ float wf[64][64];   // [step][chunk_local*8 + k]
  __shared__ float red[256];
  __shared__ float m8[8][64];    // 8 chunk matrices
  __shared__ float l2m[4][64];   // final-combine wave partials
  __shared__ int s_tick;
  const int t = threadIdx.x;
  const int b = blockIdx.x;
  const float b2v = b2[0];
  float gold = 0.f;
#pragma unroll
  for (int it = 0; it < 4; ++it) {
    const int e4 = t + (it << 8);
    const int gidx = (b << 10) + e4;
    float4 s0 = *(const float4*)&g_part[gidx << 2];
    float4 s1 = *(const float4*)&g_part[NEDGE + (gidx << 2)];
    float4 s2 = *(const float4*)&g_part[2 * NEDGE + (gidx << 2)];
    float4 s3 = *(const float4*)&g_part[3 * NEDGE + (gidx << 2)];
    float d0 = s0.x + s1.x + s2.x + s3.x + b2v;
    float d1 = s0.y + s1.y + s2.y + s3.y + b2v;
    float d2 = s0.z + s1.z + s2.z + s3.z + b2v;
    float d3 = s0.w + s1.w + s2.w + s3.w + b2v;
    d0 = fmaxf(d0, 0.f) + log1pf(__expf(-fabsf(d0)));
    d1 = fmaxf(d1, 0.f) + log1pf(__expf(-fabsf(d1)));
    d2 = fmaxf(d2, 0.f) + log1pf(__expf(-fabsf(d2)));
    d3 = fmaxf(d3, 0.f) + log1pf(__expf(-fabsf(d3)));
    const int q = e4 << 2;
    const int cl = q >> 9, r = q & 511;
    const int s = r >> 3, kk = r & 7;
    *(float4*)&wf[s][(cl << 3) + kk] = make_float4(d0, d1, d2, d3);
    if ((t & 1) == 0) gold += d0;  // k==0 edges (gold path)
  }
  red[t] = gold;
  __syncthreads();
  if (b == 0 && t == 0) {
    // node i = s+1 has valid preds kk <= s only: poison invalid d with +1e30
    for (int s = 0; s < 7; ++s)
      for (int kk = s + 1; kk < 8; ++kk) wf[s][kk] = 1e30f;
  }
  for (int o = 128; o > 0; o >>= 1) {
    __syncthreads();
    if (t < o) red[t] += red[t + o];
  }
  __syncthreads();
  if (t == 0) atomicAdd(&g_gold, red[0]);
  if (t < 64) {  // wave 0: 8 chunk recurrences (8 lanes each)
    const int g = t >> 3, j = t & 7;
    float P[8];
#pragma unroll
    for (int kk = 0; kk < 8; ++kk) P[kk] = (kk == j) ? 0.f : NEG;
    for (int s = 0; s < 64; ++s) {
      const float* wp = &wf[s][g << 3];
      float4 wa = *(const float4*)wp;
      float4 wb = *(const float4*)(wp + 4);
      float nv = lse8(P[0] - wa.x, P[1] - wa.y, P[2] - wa.z, P[3] - wa.w,
                      P[4] - wb.x, P[5] - wb.y, P[6] - wb.z, P[7] - wb.w);
#pragma unroll
      for (int kk = 7; kk > 0; --kk) P[kk] = P[kk - 1];
      P[0] = nv;
    }
#pragma unroll
    for (int kk = 0; kk < 8; ++kk) m8[g][(kk << 3) + j] = P[kk];  // row-major
    // Combine 8 chunk mats -> segment mat (in-wave, DS ops in-order).
    const int i8 = (t >> 3) << 3;
    float R = m8[0][t];
#pragma unroll
    for (int g2 = 1; g2 < 8; ++g2) R = comb8(m8[g2][t], R, i8, j);
    g_mats[(b << 6) + t] = R;
  }
  __threadfence();
  __syncthreads();
  if (t == 0) s_tick = atomicAdd(&g_done, 1);
  __syncthreads();
  if (s_tick != 31) return;
  __threadfence();  // acquire: all 32 segment mats + gold adds visible

  // Final combine of 32 segment matrices. Wave w: segs 8w..8w+7 (newest-first).
  {
    const int l = t & 63, w = t >> 6;
    const int i8 = (l >> 3) << 3, j = l & 7;
    float G = g_mats[((w << 3) << 6) + l];
#pragma unroll
    for (int s2 = 1; s2 < 8; ++s2)
      G = comb8(g_mats[(((w << 3) + s2) << 6) + l], G, i8, j);
    l2m[w][l] = G;
    __syncthreads();
    if (t < 64) {
      float G2 = l2m[0][t];
#pragma unroll
      for (int w2 = 1; w2 < 4; ++w2) G2 = comb8(l2m[w2][t], G2, i8, j);
      if (t == 0) {
        out[0] = g_gold + G2;  // gold + (prod)[0][0]
        g_gold = 0.f;          // reset for next launch / graph replay
        g_done = 0;
      }
    }
  }
}

extern "C" void kernel_launch(void* const* d_in, const int* in_sizes, int n_in,
                              void* d_out, int out_size, void* d_ws, size_t ws_size,
                              hipStream_t stream) {
  const float* emb = (const float*)d_in[0];
  const float* W1 = (const float*)d_in[1];
  const float* b1 = (const float*)d_in[2];
  const float* W2 = (const float*)d_in[3];
  const float* b2 = (const float*)d_in[4];
  float* out = (float*)d_out;
  hipLaunchKernelGGL(k12_fused, dim3(4, 256), dim3(256), 0, stream, emb, W1, b1, W2);
  hipLaunchKernelGGL(k_tail, dim3(32), dim3(256), 0, stream, b2, out);
}